// Round 10
// baseline (270.596 us; speedup 1.0000x reference)
//
#include <hip/hip_runtime.h>
#include <cmath>

// ---------------- problem constants ----------------
#define NLAYERS 100      // hidden layers (scan)
#define DIN     64       // input features
#define WDIM    100      // hidden width
#define NTT     4        // 4 n-tiles of 32 (128 neuron cols; bias col = 100)
#define ROWS    32       // rows per WAVE
#define WAVES   4        // waves per block
#define BROWS   (WAVES * ROWS)   // 128 rows per block
#define KS      7        // 7 k-steps of 16 -> K=112 (useful 101)
#define KSL     4        // ks 0..3 delivered via LDS (staged, double-buffered)
#define KST     (KS - KSL)       // ks 4..6: cross-layer asm TCP loads
#define FRAGSL  (KSL * NTT)      // 16 staged frags per layer
#define FPW     (FRAGSL / WAVES) // 4 frags staged per wave

typedef _Float16 half8  __attribute__((ext_vector_type(8)));
typedef _Float16 half2v __attribute__((ext_vector_type(2)));
typedef __fp16   fp16x2 __attribute__((ext_vector_type(2)));
typedef float    f32x4  __attribute__((ext_vector_type(4)));
typedef float    f32x16 __attribute__((ext_vector_type(16)));
typedef unsigned uint4v __attribute__((ext_vector_type(4)));

// ---------------- workspace layout ----------------
// wsh: [l][ks7][nt4][lane][8] — frag stride 512 halves (1024 B).
// A-frag (32x32x16, operand-swapped W^T): lane -> neuron n = nt*32+(lane&31);
// elem j -> k = ks*16 + (lane>>5)*8 + j.
//   k<100 && n<100   -> Ws[l][k][n]
//   k==100 && n<100  -> bs[l][n]      (bias row vs h col 100 == 1.0)
//   k==100 && n==100 -> 1.0           (bias col self-sustains)
#define WSH_LAYER_HALVES (KS * NTT * 64 * 8)             // 14336 (28672 B)
#define WSH_HALVES       (NLAYERS * WSH_LAYER_HALVES)    // 1,433,600
#define W0_HALVES        (4 * NTT * 64 * 8)              // 8192 (input, K=64 = 4 ks)
#define BPAD_FLOATS      128                             // b_in padded; col 100 = 1.0
#define OFF_BPAD_B       ((WSH_HALVES + W0_HALVES) * 2)
#define OFF_WOUT_B       (OFF_BPAD_B + BPAD_FLOATS * 4)
#define WOUT_FLOATS      128

// ============================================================
// prep v2 (unchanged): one block per (l,ks); coalesced row reads ->
// 8KB LDS f32 tile [16k][128n] -> coalesced half8 frag stores.
// ============================================================
__global__ __launch_bounds__(256)
void actor_prep(const float* __restrict__ Win, const float* __restrict__ bin,
                const float* __restrict__ Ws,  const float* __restrict__ bs,
                const float* __restrict__ Wout,
                _Float16* __restrict__ wsh, _Float16* __restrict__ w0sh,
                float* __restrict__ bpad, float* __restrict__ woutp) {
    __shared__ float tile[16 * 128];
    const int bid = blockIdx.x, tid = threadIdx.x;
    if (bid < NLAYERS * KS) {                       // hidden-layer weights
        const int l = bid / KS, ks = bid % KS;
#pragma unroll
        for (int e = 0; e < 8; ++e) {
            int idx = tid + 256 * e;                // coalesced: tid fastest
            int kk = idx >> 7, nn = idx & 127;
            int k = ks * 16 + kk;
            float v = 0.f;
            if (k < WDIM && nn < WDIM)        v = Ws[(l * WDIM + k) * WDIM + nn];
            else if (k == WDIM && nn < WDIM)  v = bs[l * WDIM + nn];   // bias row
            else if (k == WDIM && nn == WDIM) v = 1.0f;                // bias col alive
            tile[idx] = v;
        }
        __syncthreads();
        const int lane = tid & 63, nt = tid >> 6;
        const int g = lane >> 5, n = nt * 32 + (lane & 31);
        half8 o;
#pragma unroll
        for (int j = 0; j < 8; ++j) o[j] = (_Float16)tile[(g * 8 + j) * 128 + n];
        *(half8*)(wsh + (((l * KS + ks) * NTT + nt) << 9) + lane * 8) = o;
        return;
    }
    int b2 = bid - NLAYERS * KS;
    if (b2 < 4) {                                   // input layer (K=64)
        const int ks = b2;
#pragma unroll
        for (int e = 0; e < 8; ++e) {
            int idx = tid + 256 * e;
            int kk = idx >> 7, nn = idx & 127;
            int k = ks * 16 + kk;                   // < 64
            tile[idx] = (nn < WDIM) ? Win[k * WDIM + nn] : 0.f;
        }
        __syncthreads();
        const int lane = tid & 63, nt = tid >> 6;
        const int g = lane >> 5, n = nt * 32 + (lane & 31);
        half8 o;
#pragma unroll
        for (int j = 0; j < 8; ++j) o[j] = (_Float16)tile[(g * 8 + j) * 128 + n];
        *(half8*)(w0sh + ((ks * NTT + nt) << 9) + lane * 8) = o;
        return;
    }
    // last block: padded b_in (col 100 = 1.0 seed) + padded W_out
    if (tid < BPAD_FLOATS) {
        bpad[tid] = (tid < WDIM) ? bin[tid] : (tid == WDIM ? 1.0f : 0.f);
    } else {
        int t = tid - BPAD_FLOATS;
        if (t < WOUT_FLOATS) woutp[t] = (t < WDIM) ? Wout[t] : 0.f;
    }
}

// async global->LDS, 16 B per lane, zero VGPR cost.
// g: per-lane source (base + lane*16B); l: WAVE-UNIFORM LDS frag base
// (HW adds lane*16). [m97: emits global_load_lds_dwordx4]
__device__ __forceinline__ void stage16(const _Float16* __restrict__ g,
                                        _Float16* l) {
    __builtin_amdgcn_global_load_lds(
        (const __attribute__((address_space(1))) unsigned*)g,
        (__attribute__((address_space(3))) unsigned*)l, 16, 0, 0);
}

// ks4..6 of one layer -> regs via VOLATILE asm global_load_dwordx4.
// Volatile asm cannot be sunk (r25: plain C loads get moved to
// just-before-use) — these are issued a FULL LAYER before consumption;
// the intervening __syncthreads' vmcnt(0) drain guarantees completion
// (rule #18: the waitcnt pass can't see asm loads, so the barrier is
// the completion guarantee; sched_barrier(0) after it stops hoisting).
__device__ __forceinline__ void tcp_load(uint4v (&w)[KST][NTT],
                                         const _Float16* __restrict__ base, int lane) {
#pragma unroll
    for (int ks = 0; ks < KST; ++ks) {
        const _Float16* bp = base + (KSL + ks) * NTT * 512 + lane * 8;
        asm volatile("global_load_dwordx4 %0, %1, off"             : "=v"(w[ks][0]) : "v"(bp));
        asm volatile("global_load_dwordx4 %0, %1, off offset:1024" : "=v"(w[ks][1]) : "v"(bp));
        asm volatile("global_load_dwordx4 %0, %1, off offset:2048" : "=v"(w[ks][2]) : "v"(bp));
        asm volatile("global_load_dwordx4 %0, %1, off offset:3072" : "=v"(w[ks][3]) : "v"(bp));
    }
}

// split fp32 -> hi/lo fp16 (layer-0 input only: keep input fidelity)
__device__ __forceinline__ void split8(const float* __restrict__ p, half8& hi, half8& lo) {
    f32x4 u0 = *(const f32x4*)p;
    f32x4 u1 = *(const f32x4*)(p + 4);
    float v[8] = {u0[0], u0[1], u0[2], u0[3], u1[0], u1[1], u1[2], u1[3]};
#pragma unroll
    for (int e = 0; e < 8; e += 2) {
        fp16x2 h = __builtin_amdgcn_cvt_pkrtz(v[e], v[e + 1]);
        float r0 = v[e]     - (float)h[0];
        float r1 = v[e + 1] - (float)h[1];
        fp16x2 l = __builtin_amdgcn_cvt_pkrtz(r0, r1);
        hi[e] = (_Float16)h[0]; hi[e + 1] = (_Float16)h[1];
        lo[e] = (_Float16)l[0]; lo[e + 1] = (_Float16)l[1];
    }
}

// RNE f16 cast pair + packed-f16 leaky -> one dword (same ops/precision
// as the original LDS epilogue: scalar RNE cast, then max(p, 0.01p) in f16)
__device__ __forceinline__ unsigned pack2(float a, float b) {
    half2v p; p[0] = (_Float16)a; p[1] = (_Float16)b;
    const half2v slope = {(_Float16)0.01f, (_Float16)0.01f};
    p = __builtin_elementwise_max(p, p * slope);
    return __builtin_bit_cast(unsigned, p);
}

// acc -> bh: leaky+f16 pack + lane-half exchange (v_permlane32_swap).
// C/D layout (m74/m101): col=b31, row=(reg&3)+8*(reg>>2)+4g. B-frag:
// lane b31 holds k=ks*16+g*8+j; j0..3 from lane b31 regs r0=8*(ks&1)+0..3,
// j4..7 from lane b31+32 same regs -> one permlane swap per dword pair.
// Bit-identical to the LDS h path (absmax constant 0.09375 since r17).
__device__ __forceinline__ void pack_bh(const f32x16 (&acc)[NTT], half8 (&bh)[KS]) {
#pragma unroll
    for (int ks = 0; ks < KS; ++ks) {
        const int r0 = 8 * (ks & 1);
        const f32x16 a = acc[ks >> 1];
        unsigned lo0 = pack2(a[r0 + 0], a[r0 + 1]);
        unsigned lo1 = pack2(a[r0 + 2], a[r0 + 3]);
        unsigned hi0 = pack2(a[r0 + 4], a[r0 + 5]);
        unsigned hi1 = pack2(a[r0 + 6], a[r0 + 7]);
        asm volatile("v_permlane32_swap_b32 %0, %1" : "+v"(lo0), "+v"(hi0));
        asm volatile("v_permlane32_swap_b32 %0, %1" : "+v"(lo1), "+v"(hi1));
        uint4v u = {lo0, lo1, hi0, hi1};
        bh[ks] = __builtin_bit_cast(half8, u);
    }
}

static __device__ const f32x16 kZero16 = {0,0,0,0, 0,0,0,0, 0,0,0,0, 0,0,0,0};

// one hidden layer body. rb: LDS buf holding W(l) ks0..3. sb: LDS buf
// to stage W(l+1) ks0..3 into. wnext: global base of W(l+1) (stage +
// tcp source). wbgC: W(l) ks4..6 (loaded LAST layer, complete since the
// last barrier's vmcnt(0) drain). wbgN: dest for W(l+1) ks4..6.
__device__ __forceinline__ void hidden_layer(
    f32x16 (&acc)[NTT], half8 (&bh)[KS],
    const _Float16* rb, _Float16* sb, const _Float16* __restrict__ wnext,
    uint4v (&wbgC)[KST][NTT], uint4v (&wbgN)[KST][NTT],
    int wid, int lane, bool dopack) {
    // (1) stage W(l+1) ks0..3 (zero-VGPR; drained at this layer's barrier)
#pragma unroll
    for (int f = 0; f < FPW; ++f) {
        const int fr = wid * FPW + f;
        stage16(wnext + fr * 512 + lane * 8, sb + fr * 512);
    }
    // (2) pinned TCP loads: W(l+1) ks4..6 -> wbgN (consumed next layer)
    tcp_load(wbgN, wnext, lane);
    // (3) ks0..3 MFMAs, W from LDS (compiler schedules ds_reads)
#pragma unroll
    for (int ks = 0; ks < KSL; ++ks)
#pragma unroll
        for (int nt = 0; nt < NTT; ++nt) {
            half8 wfrag = *(const half8*)(rb + (ks * NTT + nt) * 512 + lane * 8);
            acc[nt] = __builtin_amdgcn_mfma_f32_32x32x16_f16(
                wfrag, bh[ks], (ks == 0 ? kZero16 : acc[nt]), 0, 0, 0);
        }
    // (4) ks4..6 MFMAs from wbgC (regs; complete since last barrier)
#pragma unroll
    for (int ks = KSL; ks < KS; ++ks)
#pragma unroll
        for (int nt = 0; nt < NTT; ++nt)
            acc[nt] = __builtin_amdgcn_mfma_f32_32x32x16_f16(
                __builtin_bit_cast(half8, wbgC[ks - KSL][nt]), bh[ks], acc[nt], 0, 0, 0);
    // (5) pack next layer's input (regs only)
    if (dopack) pack_bh(acc, bh);
    __syncthreads();                         // vmcnt(0): stage + wbgN complete
    __builtin_amdgcn_sched_barrier(0);       // nothing hoists above the drain
}

// ============================================================
// Main r27: dual-pipe W delivery with CROSS-LAYER TCP lookahead.
// Post-mortem r26 (211us): TCP loads issued and consumed in the SAME
// layer -> ~300cy cover vs 400-600cy contended L2 latency -> stall at
// the mid-layer vmcnt(0) every layer. r24 (185us) = LDS-pipe bound
// (~3250cy/CU-layer delivery, TCP idle).
// Fix: ks4..6 asm loads for layer l+1 issue at the TOP of layer l,
// held in regs across the iteration (unroll-by-2, named wbgA/wbgB —
// rule #20), consumed in l+1. The end-of-layer __syncthreads vmcnt(0)
// drain sits between def and use (free: loads had a full layer) and
// IS the completion guarantee; sched_barrier(0) after it prevents
// MFMA hoisting (rule #18). No mid-layer waits at all.
// Pipes/CU-layer: LDS = 32 stage-writes + 128 ds_read_b128 ~1790cy ||
// TCP = 128 ops ~1470cy; L1 ws 28KB; L2 traffic 28KB (unchanged).
// VGPR: acc64 + bh28 + wbgA48 + wbgB48 + temps ~230 <= 256 (2 w/SIMD).
// h handoff in regs (permlane); W bytes identical -> absmax 0.09375.
// ============================================================
__global__ __launch_bounds__(256, 2)
void actor_main(const float* __restrict__ x,
                const _Float16* __restrict__ wsh,
                const _Float16* __restrict__ w0sh,
                const float* __restrict__ bpad,
                const float* __restrict__ woutp,
                const float* __restrict__ bout,
                float* __restrict__ out) {
    __shared__ __align__(16) _Float16 wlds[2 * FRAGSL * 512];  // 2 x 16KB
    const int tid  = threadIdx.x;
    const int lane = tid & 63;
    const int wid  = tid >> 6;                   // 0..3
    const int g = lane >> 5, b31 = lane & 31;
    const int rowbase = blockIdx.x * BROWS + wid * ROWS;   // my wave's 32 rows

    f32x16 acc[NTT];                 //  64 VGPR: 4 independent MFMA chains
    half8 bh[KS];                    //  28 VGPR: B-frags (next-layer input)
    uint4v wbgA[KST][NTT];           //  48 VGPR: TCP W, even layers
    uint4v wbgB[KST][NTT];           //  48 VGPR: TCP W, odd layers

    // ---- W(0): stage ks0..3 -> buf0, pinned TCP ks4..6 -> wbgA ----
#pragma unroll
    for (int f = 0; f < FPW; ++f) {
        const int fr = wid * FPW + f;
        stage16(wsh + fr * 512 + lane * 8, wlds + fr * 512);
    }
    tcp_load(wbgA, wsh, lane);

    // ---- input layer (K=64 = 4 k-steps of 16), x hi/lo f16 split ----
    {
        half8 w0[4][NTT];
#pragma unroll
        for (int ks = 0; ks < 4; ++ks)
#pragma unroll
            for (int nt = 0; nt < NTT; ++nt)
                w0[ks][nt] = *(const half8*)(w0sh + (ks * NTT + nt) * 512 + lane * 8);
#pragma unroll
        for (int nt = 0; nt < NTT; ++nt)
#pragma unroll
            for (int qd = 0; qd < 4; ++qd) {
                f32x4 tq = *(const f32x4*)(bpad + nt * 32 + 8 * qd + 4 * g);
#pragma unroll
                for (int r = 0; r < 4; ++r) acc[nt][4 * qd + r] = tq[r];
            }
        const float* xr = x + (rowbase + b31) * DIN;
#pragma unroll
        for (int ks = 0; ks < 4; ++ks) {
            half8 xhi, xlo;
            split8(xr + ks * 16 + g * 8, xhi, xlo);
#pragma unroll
            for (int nt = 0; nt < NTT; ++nt) {
                acc[nt] = __builtin_amdgcn_mfma_f32_32x32x16_f16(w0[ks][nt], xhi, acc[nt], 0, 0, 0);
                acc[nt] = __builtin_amdgcn_mfma_f32_32x32x16_f16(w0[ks][nt], xlo, acc[nt], 0, 0, 0);
            }
        }
    }
    pack_bh(acc, bh);                // h0 in regs
    __syncthreads();                 // W(0) stage + wbgA complete
    __builtin_amdgcn_sched_barrier(0);

    // -------- 100 hidden layers, unrolled by 2 (wbgA/wbgB rotate) --------
    _Float16* buf0 = wlds;
    _Float16* buf1 = wlds + FRAGSL * 512;
#pragma unroll 1
    for (int l = 0; l < NLAYERS; l += 2) {
        const int l1 = (l + 1 < NLAYERS) ? l + 1 : NLAYERS - 1;
        const int l2 = (l + 2 < NLAYERS) ? l + 2 : NLAYERS - 1;
        // even layer l: W(l) from buf0+wbgA; prefetch W(l+1) -> buf1+wbgB
        hidden_layer(acc, bh, buf0, buf1, wsh + l1 * WSH_LAYER_HALVES,
                     wbgA, wbgB, wid, lane, true);
        // odd layer l+1: W(l+1) from buf1+wbgB; prefetch W(l+2) -> buf0+wbgA
        hidden_layer(acc, bh, buf1, buf0, wsh + l2 * WSH_LAYER_HALVES,
                     wbgB, wbgA, wid, lane, l + 1 < NLAYERS - 1);
    }
    // acc[nt] = pre-activation of layer 99 (f32) for all 128 neurons

    // ---------------- head: leaky + dot(W_out), wave-local ----------------
    float s = 0.f;
#pragma unroll
    for (int nt = 0; nt < NTT; ++nt)
#pragma unroll
        for (int qd = 0; qd < 4; ++qd) {
            f32x4 w4 = *(const f32x4*)(woutp + nt * 32 + 8 * qd + 4 * g);
#pragma unroll
            for (int r = 0; r < 4; ++r) {
                float a = acc[nt][4 * qd + r];
                float v = fmaxf(a, 0.01f * a);
                s += v * w4[r];
            }
        }
    s += __shfl_xor(s, 32);          // combine the two k-groups (same batch row)
    if (lane < 32) {
        float tot = s + bout[0];
        out[rowbase + b31] = tanhf(tot) * 4.5f + 5.5f;   // (tanh+1)/2*9 + 1
    }
}

extern "C" void kernel_launch(void* const* d_in, const int* in_sizes, int n_in,
                              void* d_out, int out_size, void* d_ws, size_t ws_size,
                              hipStream_t stream) {
    const float* x    = (const float*)d_in[0];
    const float* Win  = (const float*)d_in[1];
    const float* bin  = (const float*)d_in[2];
    const float* Ws   = (const float*)d_in[3];
    const float* bs   = (const float*)d_in[4];
    const float* Wout = (const float*)d_in[5];
    const float* bout = (const float*)d_in[6];
    float* out = (float*)d_out;

    char* ws = (char*)d_ws;
    _Float16* wsh  = (_Float16*)ws;
    _Float16* w0sh = wsh + WSH_HALVES;
    float* bpad  = (float*)(ws + OFF_BPAD_B);
    float* woutp = (float*)(ws + OFF_WOUT_B);

    hipLaunchKernelGGL(actor_prep, dim3(NLAYERS * KS + 4 + 1), dim3(256), 0, stream,
                       Win, bin, Ws, bs, Wout, wsh, w0sh, bpad, woutp);

    const int nrows = in_sizes[0] / DIN;   // 65536
    hipLaunchKernelGGL(actor_main, dim3(nrows / BROWS), dim3(WAVES * 64), 0, stream,
                       x, wsh, w0sh, bpad, woutp, bout, out);
}

// Round 11
// 259.536 us; speedup vs baseline: 1.0426x; 1.0426x over previous
//
#include <hip/hip_runtime.h>
#include <cmath>

// ---------------- problem constants ----------------
#define NLAYERS 100      // hidden layers (scan)
#define DIN     64       // input features
#define WDIM    100      // hidden width
#define NTT     4        // 4 n-tiles of 32 (128 neuron cols; bias col = 100)
#define ROWS    32       // rows per WAVE
#define WAVES   4        // waves per block
#define BROWS   (WAVES * ROWS)   // 128 rows per block
#define KS      7        // 7 k-steps of 16 -> K=112 (useful 101)
#define KSL     4        // ks 0..3 via LDS (staged, double-buffered)
#define KST     (KS - KSL)       // ks 4..6 via in-layer pinned TCP loads
#define FRAGSL  (KSL * NTT)      // 16 staged frags per layer
#define FPW     (FRAGSL / WAVES) // 4 frags staged per wave

typedef _Float16 half8  __attribute__((ext_vector_type(8)));
typedef _Float16 half2v __attribute__((ext_vector_type(2)));
typedef __fp16   fp16x2 __attribute__((ext_vector_type(2)));
typedef float    f32x4  __attribute__((ext_vector_type(4)));
typedef float    f32x16 __attribute__((ext_vector_type(16)));
typedef unsigned uint4v __attribute__((ext_vector_type(4)));

// ---------------- workspace layout ----------------
// wsh: [l][ks7][nt4][lane][8] — frag stride 512 halves (1024 B).
// A-frag (32x32x16, operand-swapped W^T): lane -> neuron n = nt*32+(lane&31);
// elem j -> k = ks*16 + (lane>>5)*8 + j.
//   k<100 && n<100   -> Ws[l][k][n]
//   k==100 && n<100  -> bs[l][n]      (bias row vs h col 100 == 1.0)
//   k==100 && n==100 -> 1.0           (bias col self-sustains)
#define WSH_LAYER_HALVES (KS * NTT * 64 * 8)             // 14336 (28672 B)
#define WSH_HALVES       (NLAYERS * WSH_LAYER_HALVES)    // 1,433,600
#define W0_HALVES        (4 * NTT * 64 * 8)              // 8192 (input, K=64 = 4 ks)
#define BPAD_FLOATS      128                             // b_in padded; col 100 = 1.0
#define OFF_BPAD_B       ((WSH_HALVES + W0_HALVES) * 2)
#define OFF_WOUT_B       (OFF_BPAD_B + BPAD_FLOATS * 4)
#define WOUT_FLOATS      128

// ============================================================
// prep v2 (unchanged): one block per (l,ks); coalesced row reads ->
// 8KB LDS f32 tile [16k][128n] -> coalesced half8 frag stores.
// ============================================================
__global__ __launch_bounds__(256)
void actor_prep(const float* __restrict__ Win, const float* __restrict__ bin,
                const float* __restrict__ Ws,  const float* __restrict__ bs,
                const float* __restrict__ Wout,
                _Float16* __restrict__ wsh, _Float16* __restrict__ w0sh,
                float* __restrict__ bpad, float* __restrict__ woutp) {
    __shared__ float tile[16 * 128];
    const int bid = blockIdx.x, tid = threadIdx.x;
    if (bid < NLAYERS * KS) {                       // hidden-layer weights
        const int l = bid / KS, ks = bid % KS;
#pragma unroll
        for (int e = 0; e < 8; ++e) {
            int idx = tid + 256 * e;                // coalesced: tid fastest
            int kk = idx >> 7, nn = idx & 127;
            int k = ks * 16 + kk;
            float v = 0.f;
            if (k < WDIM && nn < WDIM)        v = Ws[(l * WDIM + k) * WDIM + nn];
            else if (k == WDIM && nn < WDIM)  v = bs[l * WDIM + nn];   // bias row
            else if (k == WDIM && nn == WDIM) v = 1.0f;                // bias col alive
            tile[idx] = v;
        }
        __syncthreads();
        const int lane = tid & 63, nt = tid >> 6;
        const int g = lane >> 5, n = nt * 32 + (lane & 31);
        half8 o;
#pragma unroll
        for (int j = 0; j < 8; ++j) o[j] = (_Float16)tile[(g * 8 + j) * 128 + n];
        *(half8*)(wsh + (((l * KS + ks) * NTT + nt) << 9) + lane * 8) = o;
        return;
    }
    int b2 = bid - NLAYERS * KS;
    if (b2 < 4) {                                   // input layer (K=64)
        const int ks = b2;
#pragma unroll
        for (int e = 0; e < 8; ++e) {
            int idx = tid + 256 * e;
            int kk = idx >> 7, nn = idx & 127;
            int k = ks * 16 + kk;                   // < 64
            tile[idx] = (nn < WDIM) ? Win[k * WDIM + nn] : 0.f;
        }
        __syncthreads();
        const int lane = tid & 63, nt = tid >> 6;
        const int g = lane >> 5, n = nt * 32 + (lane & 31);
        half8 o;
#pragma unroll
        for (int j = 0; j < 8; ++j) o[j] = (_Float16)tile[(g * 8 + j) * 128 + n];
        *(half8*)(w0sh + ((ks * NTT + nt) << 9) + lane * 8) = o;
        return;
    }
    // last block: padded b_in (col 100 = 1.0 seed) + padded W_out
    if (tid < BPAD_FLOATS) {
        bpad[tid] = (tid < WDIM) ? bin[tid] : (tid == WDIM ? 1.0f : 0.f);
    } else {
        int t = tid - BPAD_FLOATS;
        if (t < WOUT_FLOATS) woutp[t] = (t < WDIM) ? Wout[t] : 0.f;
    }
}

// async global->LDS, 16 B per lane, zero VGPR cost.
// g: per-lane source (base + lane*16B); l: WAVE-UNIFORM LDS frag base
// (HW adds lane*16). [m97: emits global_load_lds_dwordx4]
__device__ __forceinline__ void stage16(const _Float16* __restrict__ g,
                                        _Float16* l) {
    __builtin_amdgcn_global_load_lds(
        (const __attribute__((address_space(1))) unsigned*)g,
        (__attribute__((address_space(3))) unsigned*)l, 16, 0, 0);
}

// split fp32 -> hi/lo fp16 (layer-0 input only: keep input fidelity)
__device__ __forceinline__ void split8(const float* __restrict__ p, half8& hi, half8& lo) {
    f32x4 u0 = *(const f32x4*)p;
    f32x4 u1 = *(const f32x4*)(p + 4);
    float v[8] = {u0[0], u0[1], u0[2], u0[3], u1[0], u1[1], u1[2], u1[3]};
#pragma unroll
    for (int e = 0; e < 8; e += 2) {
        fp16x2 h = __builtin_amdgcn_cvt_pkrtz(v[e], v[e + 1]);
        float r0 = v[e]     - (float)h[0];
        float r1 = v[e + 1] - (float)h[1];
        fp16x2 l = __builtin_amdgcn_cvt_pkrtz(r0, r1);
        hi[e] = (_Float16)h[0]; hi[e + 1] = (_Float16)h[1];
        lo[e] = (_Float16)l[0]; lo[e + 1] = (_Float16)l[1];
    }
}

// RNE f16 cast pair + packed-f16 leaky -> one dword (same ops/precision
// as the original LDS epilogue: scalar RNE cast, then max(p, 0.01p) in f16)
__device__ __forceinline__ unsigned pack2(float a, float b) {
    half2v p; p[0] = (_Float16)a; p[1] = (_Float16)b;
    const half2v slope = {(_Float16)0.01f, (_Float16)0.01f};
    p = __builtin_elementwise_max(p, p * slope);
    return __builtin_bit_cast(unsigned, p);
}

// acc -> bh: leaky+f16 pack + lane-half exchange (v_permlane32_swap).
// C/D layout (m74/m101): col=b31, row=(reg&3)+8*(reg>>2)+4g. B-frag:
// lane b31 holds k=ks*16+g*8+j; j0..3 from lane b31 regs r0=8*(ks&1)+0..3,
// j4..7 from lane b31+32 same regs -> one permlane swap per dword pair.
// Bit-identical to the LDS h path (absmax constant 0.09375 since r17).
__device__ __forceinline__ void pack_bh(const f32x16 (&acc)[NTT], half8 (&bh)[KS]) {
#pragma unroll
    for (int ks = 0; ks < KS; ++ks) {
        const int r0 = 8 * (ks & 1);
        const f32x16 a = acc[ks >> 1];
        unsigned lo0 = pack2(a[r0 + 0], a[r0 + 1]);
        unsigned lo1 = pack2(a[r0 + 2], a[r0 + 3]);
        unsigned hi0 = pack2(a[r0 + 4], a[r0 + 5]);
        unsigned hi1 = pack2(a[r0 + 6], a[r0 + 7]);
        asm volatile("v_permlane32_swap_b32 %0, %1" : "+v"(lo0), "+v"(hi0));
        asm volatile("v_permlane32_swap_b32 %0, %1" : "+v"(lo1), "+v"(hi1));
        uint4v u = {lo0, lo1, hi0, hi1};
        bh[ks] = __builtin_bit_cast(half8, u);
    }
}

static __device__ const f32x16 kZero16 = {0,0,0,0, 0,0,0,0, 0,0,0,0, 0,0,0,0};

// ============================================================
// Main r28: r24 base (32-row waves, 4-wave blocks, 2 blk/CU, 2 w/SIMD,
// 185us) + dual-pipe W with IN-LAYER TCP and COUNTED vmcnt(4).
// Post-mortems r25/r26/r27:
//  - r25: plain C global loads -> compiler sinks to use (stall/ks).
//  - r26: asm loads, but stages issued BEFORE TCP and vmcnt(0) —
//    vmcnt retires IN ISSUE ORDER (m135), so waiting for the TCP
//    forced draining the slow L2 stage reads too. 211us.
//  - r27: cross-layer TCP regs blew the budget (96 extra live) ->
//    VGPR=108 means compiler parked state in AGPRs and shuttled
//    v_accvgpr every layer. 211us.
// r28 fixes all three: TCP loads are asm-pinned (no sinking), issued
// FIRST (oldest in vmcnt queue), stages issued AFTER (newest), the
// mid-layer wait is vmcnt(4) = drain exactly the 12 TCP loads, leave
// the 4 stages in flight for the end-of-layer barrier (full-layer
// slack). No cross-layer TCP buffer -> ~170 VGPR, no AGPR shuttle.
// Cover for TCP: ks0..3's LDS-paced MFMAs (~1000+cy).
// Pipes/CU-layer (LDS ~85 B/cy [m134, matches r24's wall], L1 ~64):
// LDS = 128 reads + 32 stage-writes ~ 1880cy || L1 = 96 TCP + 32
// stage-reads ~ 2000cy, balanced. Expected wall ~3100cy ~ 130us.
// Rule #18: sched_barrier(0) after the counted wait (MFMAs are
// register-only and would hoist past an asm waitcnt).
// h handoff in regs (permlane); W bytes identical -> absmax 0.09375.
// Pre-committed: >=180us -> dual-pipe abandoned, revert to r24.
// ============================================================
__global__ __launch_bounds__(256, 2)
void actor_main(const float* __restrict__ x,
                const _Float16* __restrict__ wsh,
                const _Float16* __restrict__ w0sh,
                const float* __restrict__ bpad,
                const float* __restrict__ woutp,
                const float* __restrict__ bout,
                float* __restrict__ out) {
    __shared__ __align__(16) _Float16 wlds[2 * FRAGSL * 512];  // 2 x 16KB
    const int tid  = threadIdx.x;
    const int lane = tid & 63;
    const int wid  = tid >> 6;                   // 0..3
    const int g = lane >> 5, b31 = lane & 31;
    const int rowbase = blockIdx.x * BROWS + wid * ROWS;   // my wave's 32 rows

    f32x16 acc[NTT];                 //  64 VGPR: 4 independent MFMA chains
    half8 bh[KS];                    //  28 VGPR: B-frags (next-layer input)

    // ---- stage W(0) ks0..3 -> buf0 (async; overlaps input layer) ----
#pragma unroll
    for (int f = 0; f < FPW; ++f) {
        const int fr = wid * FPW + f;
        stage16(wsh + fr * 512 + lane * 8, wlds + fr * 512);
    }

    // ---- input layer (K=64 = 4 k-steps of 16), x hi/lo f16 split ----
    {
        half8 w0[4][NTT];
#pragma unroll
        for (int ks = 0; ks < 4; ++ks)
#pragma unroll
            for (int nt = 0; nt < NTT; ++nt)
                w0[ks][nt] = *(const half8*)(w0sh + (ks * NTT + nt) * 512 + lane * 8);
#pragma unroll
        for (int nt = 0; nt < NTT; ++nt)
#pragma unroll
            for (int qd = 0; qd < 4; ++qd) {
                f32x4 tq = *(const f32x4*)(bpad + nt * 32 + 8 * qd + 4 * g);
#pragma unroll
                for (int r = 0; r < 4; ++r) acc[nt][4 * qd + r] = tq[r];
            }
        const float* xr = x + (rowbase + b31) * DIN;
#pragma unroll
        for (int ks = 0; ks < 4; ++ks) {
            half8 xhi, xlo;
            split8(xr + ks * 16 + g * 8, xhi, xlo);
#pragma unroll
            for (int nt = 0; nt < NTT; ++nt) {
                acc[nt] = __builtin_amdgcn_mfma_f32_32x32x16_f16(w0[ks][nt], xhi, acc[nt], 0, 0, 0);
                acc[nt] = __builtin_amdgcn_mfma_f32_32x32x16_f16(w0[ks][nt], xlo, acc[nt], 0, 0, 0);
            }
        }
    }
    pack_bh(acc, bh);                // h0 in regs
    __syncthreads();                 // drains W(0) staging (vmcnt(0) + barrier)

    // -------- 100 hidden layers: dual-pipe, counted vmcnt, 1 barrier -------
#pragma unroll 1
    for (int l = 0; l < NLAYERS; ++l) {
        const _Float16* rb = wlds + (l & 1) * (FRAGSL * 512);      // W(l) ks0..3
        _Float16* sb = wlds + ((l + 1) & 1) * (FRAGSL * 512);      // W(l+1) dest
        const _Float16* wg = wsh + l * WSH_LAYER_HALVES;           // W(l) global
        const int ln = (l + 1 < NLAYERS) ? l + 1 : NLAYERS - 1;
        const _Float16* wn = wsh + ln * WSH_LAYER_HALVES;

        // (a) TCP loads FIRST (oldest in the vmcnt queue): W(l) ks4..6
        //     12 x pinned volatile global_load_dwordx4 (cannot sink)
        uint4v wbg[KST][NTT];
#pragma unroll
        for (int ks = 0; ks < KST; ++ks) {
            const _Float16* bp = wg + (KSL + ks) * NTT * 512 + lane * 8;
            asm volatile("global_load_dwordx4 %0, %1, off"             : "=v"(wbg[ks][0]) : "v"(bp));
            asm volatile("global_load_dwordx4 %0, %1, off offset:1024" : "=v"(wbg[ks][1]) : "v"(bp));
            asm volatile("global_load_dwordx4 %0, %1, off offset:2048" : "=v"(wbg[ks][2]) : "v"(bp));
            asm volatile("global_load_dwordx4 %0, %1, off offset:3072" : "=v"(wbg[ks][3]) : "v"(bp));
        }
        // (b) stages SECOND (newest in queue; drained only at the barrier)
#pragma unroll
        for (int f = 0; f < FPW; ++f) {
            const int fr = wid * FPW + f;
            stage16(wn + fr * 512 + lane * 8, sb + fr * 512);
        }
        // (c) ks0..3 MFMAs from LDS (JIT ds_reads; ~1000+cy of TCP cover)
#pragma unroll
        for (int ks = 0; ks < KSL; ++ks)
#pragma unroll
            for (int nt = 0; nt < NTT; ++nt) {
                half8 wfrag = *(const half8*)(rb + (ks * NTT + nt) * 512 + lane * 8);
                acc[nt] = __builtin_amdgcn_mfma_f32_32x32x16_f16(
                    wfrag, bh[ks], (ks == 0 ? kZero16 : acc[nt]), 0, 0, 0);
            }
        // (d) counted wait: drain exactly the 12 TCP loads (oldest),
        //     leave the 4 stages in flight. Dest regs threaded "+v";
        //     sched_barrier stops MFMA hoisting (rule #18).
        asm volatile("s_waitcnt vmcnt(4)"
                     : "+v"(wbg[0][0]), "+v"(wbg[0][1]), "+v"(wbg[0][2]), "+v"(wbg[0][3]),
                       "+v"(wbg[1][0]), "+v"(wbg[1][1]), "+v"(wbg[1][2]), "+v"(wbg[1][3]),
                       "+v"(wbg[2][0]), "+v"(wbg[2][1]), "+v"(wbg[2][2]), "+v"(wbg[2][3])
                     :: "memory");
        __builtin_amdgcn_sched_barrier(0);
        // (e) ks4..6 MFMAs from TCP regs
#pragma unroll
        for (int ks = KSL; ks < KS; ++ks)
#pragma unroll
            for (int nt = 0; nt < NTT; ++nt)
                acc[nt] = __builtin_amdgcn_mfma_f32_32x32x16_f16(
                    __builtin_bit_cast(half8, wbg[ks - KSL][nt]), bh[ks], acc[nt], 0, 0, 0);
        // (f) pack next layer's input (regs only)
        if (l < NLAYERS - 1)
            pack_bh(acc, bh);
        __syncthreads();             // stages drained + buffers flip
    }
    // acc[nt] = pre-activation of layer 99 (f32) for all 128 neurons

    // ---------------- head: leaky + dot(W_out), wave-local ----------------
    float s = 0.f;
#pragma unroll
    for (int nt = 0; nt < NTT; ++nt)
#pragma unroll
        for (int qd = 0; qd < 4; ++qd) {
            f32x4 w4 = *(const f32x4*)(woutp + nt * 32 + 8 * qd + 4 * g);
#pragma unroll
            for (int r = 0; r < 4; ++r) {
                float a = acc[nt][4 * qd + r];
                float v = fmaxf(a, 0.01f * a);
                s += v * w4[r];
            }
        }
    s += __shfl_xor(s, 32);          // combine the two k-groups (same batch row)
    if (lane < 32) {
        float tot = s + bout[0];
        out[rowbase + b31] = tanhf(tot) * 4.5f + 5.5f;   // (tanh+1)/2*9 + 1
    }
}

extern "C" void kernel_launch(void* const* d_in, const int* in_sizes, int n_in,
                              void* d_out, int out_size, void* d_ws, size_t ws_size,
                              hipStream_t stream) {
    const float* x    = (const float*)d_in[0];
    const float* Win  = (const float*)d_in[1];
    const float* bin  = (const float*)d_in[2];
    const float* Ws   = (const float*)d_in[3];
    const float* bs   = (const float*)d_in[4];
    const float* Wout = (const float*)d_in[5];
    const float* bout = (const float*)d_in[6];
    float* out = (float*)d_out;

    char* ws = (char*)d_ws;
    _Float16* wsh  = (_Float16*)ws;
    _Float16* w0sh = wsh + WSH_HALVES;
    float* bpad  = (float*)(ws + OFF_BPAD_B);
    float* woutp = (float*)(ws + OFF_WOUT_B);

    hipLaunchKernelGGL(actor_prep, dim3(NLAYERS * KS + 4 + 1), dim3(256), 0, stream,
                       Win, bin, Ws, bs, Wout, wsh, w0sh, bpad, woutp);

    const int nrows = in_sizes[0] / DIN;   // 65536
    hipLaunchKernelGGL(actor_main, dim3(nrows / BROWS), dim3(WAVES * 64), 0, stream,
                       x, wsh, w0sh, bpad, woutp, bout, out);
}

// Round 12
// 243.145 us; speedup vs baseline: 1.1129x; 1.0674x over previous
//
#include <hip/hip_runtime.h>
#include <cmath>

// ---------------- problem constants ----------------
#define NLAYERS 100      // hidden layers (scan)
#define DIN     64       // input features
#define WDIM    100      // hidden width
#define NTT     4        // 4 n-tiles of 32 (128 neuron cols; bias col = 100)
#define ROWS    32       // rows per WAVE
#define WAVES   4        // waves per block
#define BROWS   (WAVES * ROWS)   // 128 rows per block
#define KS      7        // 7 k-steps of 16 -> K=112 (useful 101)
#define FRAGS   (KS * NTT)       // 28 W frags per layer
#define FPW     (FRAGS / WAVES)  // 7 frags staged per wave

typedef _Float16 half8  __attribute__((ext_vector_type(8)));
typedef _Float16 half2v __attribute__((ext_vector_type(2)));
typedef __fp16   fp16x2 __attribute__((ext_vector_type(2)));
typedef float    f32x4  __attribute__((ext_vector_type(4)));
typedef float    f32x16 __attribute__((ext_vector_type(16)));
typedef unsigned uint4v __attribute__((ext_vector_type(4)));

// ---------------- workspace layout ----------------
// wsh: [l][ks7][nt4][lane][8] — frag stride 512 halves (1024 B).
// A-frag (32x32x16, operand-swapped W^T): lane -> neuron n = nt*32+(lane&31);
// elem j -> k = ks*16 + (lane>>5)*8 + j.
//   k<100 && n<100   -> Ws[l][k][n]
//   k==100 && n<100  -> bs[l][n]      (bias row vs h col 100 == 1.0)
//   k==100 && n==100 -> 1.0           (bias col self-sustains)
// Frag layout == the global_load_lds pattern: per-lane 16B contiguous
// source, wave-uniform LDS destination base.
#define WSH_LAYER_HALVES (KS * NTT * 64 * 8)             // 14336 (28672 B)
#define WSH_HALVES       (NLAYERS * WSH_LAYER_HALVES)    // 1,433,600
#define W0_HALVES        (4 * NTT * 64 * 8)              // 8192 (input, K=64 = 4 ks)
#define BPAD_FLOATS      128                             // b_in padded; col 100 = 1.0
#define OFF_BPAD_B       ((WSH_HALVES + W0_HALVES) * 2)
#define OFF_WOUT_B       (OFF_BPAD_B + BPAD_FLOATS * 4)
#define WOUT_FLOATS      128

// ============================================================
// prep v2 (unchanged): one block per (l,ks); coalesced row reads ->
// 8KB LDS f32 tile [16k][128n] -> coalesced half8 frag stores.
// ============================================================
__global__ __launch_bounds__(256)
void actor_prep(const float* __restrict__ Win, const float* __restrict__ bin,
                const float* __restrict__ Ws,  const float* __restrict__ bs,
                const float* __restrict__ Wout,
                _Float16* __restrict__ wsh, _Float16* __restrict__ w0sh,
                float* __restrict__ bpad, float* __restrict__ woutp) {
    __shared__ float tile[16 * 128];
    const int bid = blockIdx.x, tid = threadIdx.x;
    if (bid < NLAYERS * KS) {                       // hidden-layer weights
        const int l = bid / KS, ks = bid % KS;
#pragma unroll
        for (int e = 0; e < 8; ++e) {
            int idx = tid + 256 * e;                // coalesced: tid fastest
            int kk = idx >> 7, nn = idx & 127;
            int k = ks * 16 + kk;
            float v = 0.f;
            if (k < WDIM && nn < WDIM)        v = Ws[(l * WDIM + k) * WDIM + nn];
            else if (k == WDIM && nn < WDIM)  v = bs[l * WDIM + nn];   // bias row
            else if (k == WDIM && nn == WDIM) v = 1.0f;                // bias col alive
            tile[idx] = v;
        }
        __syncthreads();
        const int lane = tid & 63, nt = tid >> 6;
        const int g = lane >> 5, n = nt * 32 + (lane & 31);
        half8 o;
#pragma unroll
        for (int j = 0; j < 8; ++j) o[j] = (_Float16)tile[(g * 8 + j) * 128 + n];
        *(half8*)(wsh + (((l * KS + ks) * NTT + nt) << 9) + lane * 8) = o;
        return;
    }
    int b2 = bid - NLAYERS * KS;
    if (b2 < 4) {                                   // input layer (K=64)
        const int ks = b2;
#pragma unroll
        for (int e = 0; e < 8; ++e) {
            int idx = tid + 256 * e;
            int kk = idx >> 7, nn = idx & 127;
            int k = ks * 16 + kk;                   // < 64
            tile[idx] = (nn < WDIM) ? Win[k * WDIM + nn] : 0.f;
        }
        __syncthreads();
        const int lane = tid & 63, nt = tid >> 6;
        const int g = lane >> 5, n = nt * 32 + (lane & 31);
        half8 o;
#pragma unroll
        for (int j = 0; j < 8; ++j) o[j] = (_Float16)tile[(g * 8 + j) * 128 + n];
        *(half8*)(w0sh + ((ks * NTT + nt) << 9) + lane * 8) = o;
        return;
    }
    // last block: padded b_in (col 100 = 1.0 seed) + padded W_out
    if (tid < BPAD_FLOATS) {
        bpad[tid] = (tid < WDIM) ? bin[tid] : (tid == WDIM ? 1.0f : 0.f);
    } else {
        int t = tid - BPAD_FLOATS;
        if (t < WOUT_FLOATS) woutp[t] = (t < WDIM) ? Wout[t] : 0.f;
    }
}

// async global->LDS, 16 B per lane, zero VGPR cost.
// g: per-lane source (base + lane*16B); l: WAVE-UNIFORM LDS frag base
// (HW adds lane*16). [m97: emits global_load_lds_dwordx4]
__device__ __forceinline__ void stage16(const _Float16* __restrict__ g,
                                        _Float16* l) {
    __builtin_amdgcn_global_load_lds(
        (const __attribute__((address_space(1))) unsigned*)g,
        (__attribute__((address_space(3))) unsigned*)l, 16, 0, 0);
}

// split fp32 -> hi/lo fp16 (layer-0 input only: keep input fidelity)
__device__ __forceinline__ void split8(const float* __restrict__ p, half8& hi, half8& lo) {
    f32x4 u0 = *(const f32x4*)p;
    f32x4 u1 = *(const f32x4*)(p + 4);
    float v[8] = {u0[0], u0[1], u0[2], u0[3], u1[0], u1[1], u1[2], u1[3]};
#pragma unroll
    for (int e = 0; e < 8; e += 2) {
        fp16x2 h = __builtin_amdgcn_cvt_pkrtz(v[e], v[e + 1]);
        float r0 = v[e]     - (float)h[0];
        float r1 = v[e + 1] - (float)h[1];
        fp16x2 l = __builtin_amdgcn_cvt_pkrtz(r0, r1);
        hi[e] = (_Float16)h[0]; hi[e + 1] = (_Float16)h[1];
        lo[e] = (_Float16)l[0]; lo[e + 1] = (_Float16)l[1];
    }
}

// RNE f16 cast pair + packed-f16 leaky -> one dword (same ops/precision
// as the original LDS epilogue: scalar RNE cast, then max(p, 0.01p) in f16)
__device__ __forceinline__ unsigned pack2(float a, float b) {
    half2v p; p[0] = (_Float16)a; p[1] = (_Float16)b;
    const half2v slope = {(_Float16)0.01f, (_Float16)0.01f};
    p = __builtin_elementwise_max(p, p * slope);
    return __builtin_bit_cast(unsigned, p);
}

// acc -> bh: leaky+f16 pack + lane-half exchange (v_permlane32_swap).
// C/D layout (m74/m101): col=b31, row=(reg&3)+8*(reg>>2)+4g. B-frag:
// lane b31 holds k=ks*16+g*8+j; j0..3 from lane b31 regs r0=8*(ks&1)+0..3,
// j4..7 from lane b31+32 same regs -> one permlane swap per dword pair.
// Bit-identical to the LDS h path (absmax constant 0.09375 since r17).
__device__ __forceinline__ void pack_bh(const f32x16 (&acc)[NTT], half8 (&bh)[KS]) {
#pragma unroll
    for (int ks = 0; ks < KS; ++ks) {
        const int r0 = 8 * (ks & 1);
        const f32x16 a = acc[ks >> 1];
        unsigned lo0 = pack2(a[r0 + 0], a[r0 + 1]);
        unsigned lo1 = pack2(a[r0 + 2], a[r0 + 3]);
        unsigned hi0 = pack2(a[r0 + 4], a[r0 + 5]);
        unsigned hi1 = pack2(a[r0 + 6], a[r0 + 7]);
        asm volatile("v_permlane32_swap_b32 %0, %1" : "+v"(lo0), "+v"(hi0));
        asm volatile("v_permlane32_swap_b32 %0, %1" : "+v"(lo1), "+v"(hi1));
        uint4v u = {lo0, lo1, hi0, hi1};
        bh[ks] = __builtin_bit_cast(half8, u);
    }
}

static __device__ const f32x16 kZero16 = {0,0,0,0, 0,0,0,0, 0,0,0,0, 0,0,0,0};

// ============================================================
// Main r29 = r24 verbatim (the measured champion: 185.9us main).
// Session summary of measured structures (main dispatch):
//   r17 200us: 2-wave blocks, LDS h handoff, barrier convoy
//   r18 212us: wave-owns-nt -> 2x LDS h reads
//   r19 244us: 32-row 2-wave -> 2x VMEM + refill sunk (VGPR=56)
//   r20 240us: 1-wave barrier-free -> refill sunk (VGPR=128)
//   r21 225us: zero-LDS permlane h handoff + anchor -> anchor drains
//   r22 299us: reg W dbuf -> 296 live > 256 arch VGPRs -> scratch spill
//   r23 230us: gload_lds W + reg h, 64-row waves -> 1 wave/SIMD latency
//   r24 186us: 32-row waves, 4-wave blocks, 2 blk/CU, 2 w/SIMD  << BEST
//   r25 243us: dual-pipe, C loads -> sunk (VGPR=64)
//   r26 211us: dual-pipe, asm loads, vmcnt(0) after stages -> drains stages
//   r27 211us: dual-pipe, cross-layer regs -> AGPR shuttle (VGPR=108)
//   r28 204us: dual-pipe, counted vmcnt(4) -> mid-layer wait unhidden
//              (both waves per SIMD barrier-synced -> no cover). ABANDONED.
// r24's budget (4440cy/CU-layer): LDS delivery ~3250cy (224
// ds_read_b128 + 56 staged writes @ ~85B/cy effective) + ~1100cy
// pack/barrier/latency slack. All alternative decompositions measured
// worse (above); the duplicate-W-read cost of 8 row-parallel waves
// sharing one LDS pipe is this problem's delivery-bound plateau at
// HIP source level.
// Pipeline per layer: stage W(l+1) via global_load_lds into the other
// 28KB buffer (zero VGPR, ~full layer of slack before the barrier
// drain), ds_read W(l) -> regs (compiler-paced), 28 MFMAs (4 indep
// chains), pack_bh in regs (permlane), 1 __syncthreads.
// h handoff in regs; absmax 0.09375 (bit-identical math since r17).
// ============================================================
__global__ __launch_bounds__(256, 2)
void actor_main(const float* __restrict__ x,
                const _Float16* __restrict__ wsh,
                const _Float16* __restrict__ w0sh,
                const float* __restrict__ bpad,
                const float* __restrict__ woutp,
                const float* __restrict__ bout,
                float* __restrict__ out) {
    __shared__ __align__(16) _Float16 wlds[2 * WSH_LAYER_HALVES];  // 57344 B
    const int tid  = threadIdx.x;
    const int lane = tid & 63;
    const int wid  = tid >> 6;                   // 0..3
    const int g = lane >> 5, b31 = lane & 31;
    const int rowbase = blockIdx.x * BROWS + wid * ROWS;   // my wave's 32 rows

    f32x16 acc[NTT];                 //  64 VGPR: 4 independent MFMA chains
    half8 bh[KS];                    //  28 VGPR: B-frags (next-layer input)
    half8 wb[KS][NTT];               // W frags from LDS (compiler-paced reads)

    // ---- stage W(0) -> buf0 (async; overlaps entire input layer) ----
#pragma unroll
    for (int f = 0; f < FPW; ++f) {
        const int fr = wid * FPW + f;
        stage16(wsh + fr * 512 + lane * 8, wlds + fr * 512);
    }

    // ---- input layer (K=64 = 4 k-steps of 16), x hi/lo f16 split ----
    {
        half8 w0[4][NTT];
#pragma unroll
        for (int ks = 0; ks < 4; ++ks)
#pragma unroll
            for (int nt = 0; nt < NTT; ++nt)
                w0[ks][nt] = *(const half8*)(w0sh + (ks * NTT + nt) * 512 + lane * 8);
#pragma unroll
        for (int nt = 0; nt < NTT; ++nt)
#pragma unroll
            for (int qd = 0; qd < 4; ++qd) {
                f32x4 tq = *(const f32x4*)(bpad + nt * 32 + 8 * qd + 4 * g);
#pragma unroll
                for (int r = 0; r < 4; ++r) acc[nt][4 * qd + r] = tq[r];
            }
        const float* xr = x + (rowbase + b31) * DIN;
#pragma unroll
        for (int ks = 0; ks < 4; ++ks) {
            half8 xhi, xlo;
            split8(xr + ks * 16 + g * 8, xhi, xlo);
#pragma unroll
            for (int nt = 0; nt < NTT; ++nt) {
                acc[nt] = __builtin_amdgcn_mfma_f32_32x32x16_f16(w0[ks][nt], xhi, acc[nt], 0, 0, 0);
                acc[nt] = __builtin_amdgcn_mfma_f32_32x32x16_f16(w0[ks][nt], xlo, acc[nt], 0, 0, 0);
            }
        }
    }
    pack_bh(acc, bh);                // h0 in regs
    __syncthreads();                 // drains W(0) staging (vmcnt(0) + barrier)

    // -------- 100 hidden layers: 1 barrier/layer, zero-VGPR W pipeline ------
#pragma unroll 1
    for (int l = 0; l < NLAYERS; ++l) {
        const _Float16* rb = wlds + (l & 1) * WSH_LAYER_HALVES;        // W(l)
        _Float16* sb = wlds + ((l + 1) & 1) * WSH_LAYER_HALVES;        // W(l+1) dest
        const int ln = (l + 1 < NLAYERS) ? l + 1 : NLAYERS - 1;
        const _Float16* wn = wsh + ln * WSH_LAYER_HALVES;

        // issue next-layer staging FIRST (max slack before the barrier drain)
#pragma unroll
        for (int f = 0; f < FPW; ++f) {
            const int fr = wid * FPW + f;
            stage16(wn + fr * 512 + lane * 8, sb + fr * 512);
        }
        // full-layer W -> regs: one 28-read burst (counted lgkm; the
        // co-resident wave on this SIMD covers the burst latency)
#pragma unroll
        for (int ks = 0; ks < KS; ++ks)
#pragma unroll
            for (int nt = 0; nt < NTT; ++nt)
                wb[ks][nt] = *(const half8*)(rb + (ks * NTT + nt) * 512 + lane * 8);
        // 28 MFMAs, 4 independent chains
#pragma unroll
        for (int ks = 0; ks < KS; ++ks)
#pragma unroll
            for (int nt = 0; nt < NTT; ++nt)
                acc[nt] = __builtin_amdgcn_mfma_f32_32x32x16_f16(
                    wb[ks][nt], bh[ks], (ks == 0 ? kZero16 : acc[nt]), 0, 0, 0);
        if (l < NLAYERS - 1)
            pack_bh(acc, bh);        // next layer's input (regs only)
        __syncthreads();             // staging drained + buffers flip
    }
    // acc[nt] = pre-activation of layer 99 (f32) for all 128 neurons

    // ---------------- head: leaky + dot(W_out), wave-local ----------------
    float s = 0.f;
#pragma unroll
    for (int nt = 0; nt < NTT; ++nt)
#pragma unroll
        for (int qd = 0; qd < 4; ++qd) {
            f32x4 w4 = *(const f32x4*)(woutp + nt * 32 + 8 * qd + 4 * g);
#pragma unroll
            for (int r = 0; r < 4; ++r) {
                float a = acc[nt][4 * qd + r];
                float v = fmaxf(a, 0.01f * a);
                s += v * w4[r];
            }
        }
    s += __shfl_xor(s, 32);          // combine the two k-groups (same batch row)
    if (lane < 32) {
        float tot = s + bout[0];
        out[rowbase + b31] = tanhf(tot) * 4.5f + 5.5f;   // (tanh+1)/2*9 + 1
    }
}

extern "C" void kernel_launch(void* const* d_in, const int* in_sizes, int n_in,
                              void* d_out, int out_size, void* d_ws, size_t ws_size,
                              hipStream_t stream) {
    const float* x    = (const float*)d_in[0];
    const float* Win  = (const float*)d_in[1];
    const float* bin  = (const float*)d_in[2];
    const float* Ws   = (const float*)d_in[3];
    const float* bs   = (const float*)d_in[4];
    const float* Wout = (const float*)d_in[5];
    const float* bout = (const float*)d_in[6];
    float* out = (float*)d_out;

    char* ws = (char*)d_ws;
    _Float16* wsh  = (_Float16*)ws;
    _Float16* w0sh = wsh + WSH_HALVES;
    float* bpad  = (float*)(ws + OFF_BPAD_B);
    float* woutp = (float*)(ws + OFF_WOUT_B);

    hipLaunchKernelGGL(actor_prep, dim3(NLAYERS * KS + 4 + 1), dim3(256), 0, stream,
                       Win, bin, Ws, bs, Wout, wsh, w0sh, bpad, woutp);

    const int nrows = in_sizes[0] / DIN;   // 65536
    hipLaunchKernelGGL(actor_main, dim3(nrows / BROWS), dim3(WAVES * 64), 0, stream,
                       x, wsh, w0sh, bpad, woutp, bout, out);
}